// Round 8
// baseline (276.981 us; speedup 1.0000x reference)
//
#include <hip/hip_runtime.h>
#include <hip/hip_bf16.h>

// GCN VGAE encoder. CSR via single-pass 512-node-bucket binning (register-cached
// edges, one global read), 8-way windowed fine sort, ushort adjacency,
// gather aggregation over bf16 ts table (fp32 accum).
// norm factorization: agg[c] = dinv[c]*(sum_e ts[src] + ts[c]) + b, ts = (X@W)*dinv.

constexpr int BLK = 256;
constexpr int SH = 9;            // nodes per coarse bucket = 512
constexpr int CAP = 24576;       // slab capacity per bucket (mean ~16.3K, ~64 sigma)
constexpr int CHUNK = 2048;      // edges per block in k_bin
constexpr int EPB = CHUNK / 256; // 8 register-cached edges per thread in k_bin

typedef float vf4 __attribute__((ext_vector_type(4)));   // for nontemporal stores

__device__ __forceinline__ void fma4(float4& a, float s, const float4& w) {
    a.x = fmaf(s, w.x, a.x);
    a.y = fmaf(s, w.y, a.y);
    a.z = fmaf(s, w.z, a.z);
    a.w = fmaf(s, w.w, a.w);
}

__device__ __forceinline__ unsigned short f2bf(float f) {  // RNE
    unsigned u = __float_as_uint(f);
    return (unsigned short)((u + 0x7fffu + ((u >> 16) & 1u)) >> 16);
}

__device__ __forceinline__ void acc_bf8(float* a, uint4 v) {
    a[0] += __uint_as_float(v.x << 16);
    a[1] += __uint_as_float(v.x & 0xffff0000u);
    a[2] += __uint_as_float(v.y << 16);
    a[3] += __uint_as_float(v.y & 0xffff0000u);
    a[4] += __uint_as_float(v.z << 16);
    a[5] += __uint_as_float(v.z & 0xffff0000u);
    a[6] += __uint_as_float(v.w << 16);
    a[7] += __uint_as_float(v.w & 0xffff0000u);
}

// Single-pass binning: edges register-cached as col16<<16|row16 on the ONLY global
// read; 98-counter LDS hist -> reserve slab slice -> emit. bucket = e>>25.
__global__ __launch_bounds__(256) void k_bin(const int* __restrict__ row,
                                             const int* __restrict__ col,
                                             int* __restrict__ ccur,
                                             unsigned* __restrict__ binned,
                                             int E, int B) {
    __shared__ int h[128];
    const int tid = threadIdx.x;
    if (tid < 128) h[tid] = 0;
    __syncthreads();
    const int e0 = blockIdx.x * CHUNK;
    unsigned ebuf[EPB];
    #pragma unroll
    for (int j = 0; j < EPB; ++j) {
        int e = e0 + tid + j * 256;
        ebuf[j] = (e < E) ? (((unsigned)col[e] << 16) | (unsigned)row[e]) : 0xFFFFFFFFu;
    }
    #pragma unroll
    for (int j = 0; j < EPB; ++j)
        if (ebuf[j] != 0xFFFFFFFFu) atomicAdd(&h[ebuf[j] >> 25], 1);
    __syncthreads();
    if (tid < B) {
        int c = h[tid];
        if (c) h[tid] = atomicAdd(&ccur[tid], c);   // in-bucket base for this block
    }
    __syncthreads();
    #pragma unroll
    for (int j = 0; j < EPB; ++j) {
        unsigned e = ebuf[j];
        if (e != 0xFFFFFFFFu) {
            int b = e >> 25;
            int pos = atomicAdd(&h[b], 1);
            if (pos < CAP) binned[(size_t)b * CAP + pos] = e;
        }
    }
}

// 8 sub-blocks per bucket; sub-block w handles the 64-node window [b*512+w*64, +64).
// Pass 1: stream slab, private count of earlier-window entries (shfl-reduced) +
// 64-counter LDS hist for own window -> dinv, range2, per-node bases.
// Pass 2: stream slab, emit own window's entries as dense ushort srcidx.
__global__ __launch_bounds__(256) void k_fine(const unsigned* __restrict__ binned,
                                              const int* __restrict__ ccur,
                                              unsigned short* __restrict__ srcidx,
                                              int2* __restrict__ range2,
                                              float* __restrict__ dinv, int N) {
    __shared__ int cnt[64];
    __shared__ int beforeTot;
    const int blk = blockIdx.x;
    const int b = blk >> 3, w = blk & 7;
    const int ebase = b * CAP;
    const int ecnt = min(ccur[b], CAP);
    const int tid = threadIdx.x;
    if (tid < 64) cnt[tid] = 0;
    if (tid == 0) beforeTot = 0;
    __syncthreads();
    int myBefore = 0;
    for (int i = tid; i < ecnt; i += 256) {
        unsigned e = binned[ebase + i];
        int f = (e >> 16) & 511;
        int fw = f >> 6;
        myBefore += (fw < w) ? 1 : 0;
        if (fw == w) atomicAdd(&cnt[f & 63], 1);
    }
    #pragma unroll
    for (int off = 32; off; off >>= 1) myBefore += __shfl_down(myBefore, off, 64);
    if ((tid & 63) == 0 && myBefore) atomicAdd(&beforeTot, myBefore);
    __syncthreads();
    if (tid < 64) {
        int v = cnt[tid], s = v;
        #pragma unroll
        for (int off = 1; off < 64; off <<= 1) {
            int u = __shfl_up(s, off, 64);
            if (tid >= off) s += u;
        }
        int gbase = ebase + beforeTot + s - v;
        int n = (b << SH) + (w << 6) + tid;
        if (n < N) {
            range2[n] = make_int2(gbase, gbase + v);
            dinv[n] = rsqrtf((float)v + 1.0f);
        }
        cnt[tid] = gbase;
    }
    __syncthreads();
    for (int i = tid; i < ecnt; i += 256) {
        unsigned e = binned[ebase + i];
        int f = (e >> 16) & 511;
        if ((f >> 6) == w) {
            int pos = atomicAdd(&cnt[f & 63], 1);
            srcidx[pos] = (unsigned short)(e & 0xFFFFu);
        }
    }
}

// T[N,64](bf16) = (op(X[N,K]) @ W) * dinv[n].  4 nodes/thread to amortize LDS W-reads.
template <int K, bool RELU, bool TWO_W>
__global__ __launch_bounds__(256) void k_gemm(const float* __restrict__ X,
                                              const float* __restrict__ Wa,
                                              const float* __restrict__ Wb,
                                              const float* __restrict__ dinv,
                                              unsigned short* __restrict__ T, int N) {
    __shared__ float4 Wl[K * 16];
    const int tid = threadIdx.x;
    for (int i = tid; i < K * 16; i += 256) {
        if (TWO_W) {
            int k = i >> 4, fgi = i & 15;
            const float* s = (fgi < 8) ? (Wa + k * 32 + fgi * 4)
                                       : (Wb + k * 32 + (fgi - 8) * 4);
            Wl[i] = *reinterpret_cast<const float4*>(s);
        } else {
            Wl[i] = reinterpret_cast<const float4*>(Wa)[i];
        }
    }
    __syncthreads();

    const int fg = tid & 15;
    const int ns = tid >> 4;
    const int nb = blockIdx.x * 64;
    const float4* Xv = reinterpret_cast<const float4*>(X);
    const float4 z = make_float4(0.f, 0.f, 0.f, 0.f);
    float4 acc[4] = {z, z, z, z};
    int n[4];
    bool v[4];
    #pragma unroll
    for (int i = 0; i < 4; ++i) { n[i] = nb + ns + i * 16; v[i] = n[i] < N; }

    for (int k4 = 0; k4 < K / 4; ++k4) {
        float4 xv[4];
        #pragma unroll
        for (int i = 0; i < 4; ++i) {
            xv[i] = v[i] ? Xv[(size_t)n[i] * (K / 4) + k4] : z;
            if (RELU) {
                xv[i].x = fmaxf(xv[i].x, 0.f); xv[i].y = fmaxf(xv[i].y, 0.f);
                xv[i].z = fmaxf(xv[i].z, 0.f); xv[i].w = fmaxf(xv[i].w, 0.f);
            }
        }
        float4 w0 = Wl[(k4 * 4 + 0) * 16 + fg];
        float4 w1 = Wl[(k4 * 4 + 1) * 16 + fg];
        float4 w2 = Wl[(k4 * 4 + 2) * 16 + fg];
        float4 w3 = Wl[(k4 * 4 + 3) * 16 + fg];
        #pragma unroll
        for (int i = 0; i < 4; ++i) {
            fma4(acc[i], xv[i].x, w0); fma4(acc[i], xv[i].y, w1);
            fma4(acc[i], xv[i].z, w2); fma4(acc[i], xv[i].w, w3);
        }
    }
    #pragma unroll
    for (int i = 0; i < 4; ++i) {
        if (v[i]) {
            float d = dinv[n[i]];
            ushort4 o;
            o.x = f2bf(acc[i].x * d); o.y = f2bf(acc[i].y * d);
            o.z = f2bf(acc[i].z * d); o.w = f2bf(acc[i].w * d);
            reinterpret_cast<ushort4*>(T)[(size_t)n[i] * 16 + fg] = o;
        }
    }
}

// out[n] = dinv[n]*(sum_{k in range(n)} Ts[srcidx[k]] + Ts[n]) + bias
// 8 threads/node, 16 B (8 bf16 feats) each, fp32 accumulate; ushort4 srcidx loads,
// 8-edge unroll for MLP. SPLIT routes feats 0:32 -> out (mu), 32:64 -> out+32N.
template <bool SPLIT>
__global__ __launch_bounds__(256) void k_gather(const int2* __restrict__ range2,
                                                const unsigned short* __restrict__ srcidx,
                                                const uint4* __restrict__ Ts,
                                                const float* __restrict__ dinv,
                                                const float* __restrict__ ba,
                                                const float* __restrict__ bb,
                                                float* __restrict__ out, int N) {
    int g = blockIdx.x * BLK + threadIdx.x;
    int n = g >> 3, fg = g & 7;
    if (n >= N) return;
    int2 rg = range2[n];
    int k = rg.x, end = rg.y;
    float a[8];
    {
        uint4 s = Ts[(size_t)n * 8 + fg];   // self loop
        a[0] = __uint_as_float(s.x << 16);
        a[1] = __uint_as_float(s.x & 0xffff0000u);
        a[2] = __uint_as_float(s.y << 16);
        a[3] = __uint_as_float(s.y & 0xffff0000u);
        a[4] = __uint_as_float(s.z << 16);
        a[5] = __uint_as_float(s.z & 0xffff0000u);
        a[6] = __uint_as_float(s.w << 16);
        a[7] = __uint_as_float(s.w & 0xffff0000u);
    }
    for (; k < end && (k & 3); ++k)          // align to ushort4
        acc_bf8(a, Ts[(size_t)srcidx[k] * 8 + fg]);
    for (; k + 8 <= end; k += 8) {
        ushort4 r0 = *reinterpret_cast<const ushort4*>(srcidx + k);
        ushort4 r1 = *reinterpret_cast<const ushort4*>(srcidx + k + 4);
        uint4 v0 = Ts[(size_t)r0.x * 8 + fg];
        uint4 v1 = Ts[(size_t)r0.y * 8 + fg];
        uint4 v2 = Ts[(size_t)r0.z * 8 + fg];
        uint4 v3 = Ts[(size_t)r0.w * 8 + fg];
        uint4 v4 = Ts[(size_t)r1.x * 8 + fg];
        uint4 v5 = Ts[(size_t)r1.y * 8 + fg];
        uint4 v6 = Ts[(size_t)r1.z * 8 + fg];
        uint4 v7 = Ts[(size_t)r1.w * 8 + fg];
        acc_bf8(a, v0); acc_bf8(a, v1); acc_bf8(a, v2); acc_bf8(a, v3);
        acc_bf8(a, v4); acc_bf8(a, v5); acc_bf8(a, v6); acc_bf8(a, v7);
    }
    if (k + 4 <= end) {
        ushort4 r0 = *reinterpret_cast<const ushort4*>(srcidx + k);
        uint4 v0 = Ts[(size_t)r0.x * 8 + fg];
        uint4 v1 = Ts[(size_t)r0.y * 8 + fg];
        uint4 v2 = Ts[(size_t)r0.z * 8 + fg];
        uint4 v3 = Ts[(size_t)r0.w * 8 + fg];
        acc_bf8(a, v0); acc_bf8(a, v1); acc_bf8(a, v2); acc_bf8(a, v3);
        k += 4;
    }
    for (; k < end; ++k)
        acc_bf8(a, Ts[(size_t)srcidx[k] * 8 + fg]);

    float d = dinv[n];
    const float* bsrc;
    float* dst;
    if (SPLIT) {
        if (fg < 4) {
            bsrc = ba + fg * 8;
            dst = out + (size_t)n * 32 + fg * 8;
        } else {
            bsrc = bb + (fg - 4) * 8;
            dst = out + (size_t)N * 32 + (size_t)n * 32 + (fg - 4) * 8;
        }
    } else {
        bsrc = ba + fg * 8;
        dst = out + (size_t)n * 64 + fg * 8;
    }
    float4 b0 = reinterpret_cast<const float4*>(bsrc)[0];
    float4 b1 = reinterpret_cast<const float4*>(bsrc)[1];
    vf4 o0, o1;
    o0.x = fmaf(a[0], d, b0.x); o0.y = fmaf(a[1], d, b0.y);
    o0.z = fmaf(a[2], d, b0.z); o0.w = fmaf(a[3], d, b0.w);
    o1.x = fmaf(a[4], d, b1.x); o1.y = fmaf(a[5], d, b1.y);
    o1.z = fmaf(a[6], d, b1.z); o1.w = fmaf(a[7], d, b1.w);
    if (SPLIT) {   // final output: write-once, bypass-cache hint
        __builtin_nontemporal_store(o0, reinterpret_cast<vf4*>(dst));
        __builtin_nontemporal_store(o1, reinterpret_cast<vf4*>(dst) + 1);
    } else {
        reinterpret_cast<vf4*>(dst)[0] = o0;
        reinterpret_cast<vf4*>(dst)[1] = o1;
    }
}

extern "C" void kernel_launch(void* const* d_in, const int* in_sizes, int n_in,
                              void* d_out, int out_size, void* d_ws, size_t ws_size,
                              hipStream_t stream) {
    const float* x   = (const float*)d_in[0];
    const int*   ei  = (const int*)d_in[1];
    const float* W1  = (const float*)d_in[2];
    const float* b1  = (const float*)d_in[3];
    const float* Wmu = (const float*)d_in[4];
    const float* bmu = (const float*)d_in[5];
    const float* Wls = (const float*)d_in[6];
    const float* bls = (const float*)d_in[7];

    const int N = in_sizes[0] / 128;
    const int E = in_sizes[1] / 2;
    const int* row = ei;             // sources
    const int* col = ei + E;         // targets
    const int B = (N + 511) >> SH;   // coarse buckets (<= 128)
    const size_t BCAP = (size_t)B * CAP;

    // ws layout (4B units):
    // [0,1024) ccur | [1024, 1024+BCAP) binned (t1/t2 bf16[64N]=32N ints overlay after
    // k_fine) | srcidx ushort[BCAP] (BCAP/2 ints) | dinv[N] | range2 int2[N] | agg1 f32[64N]
    int* wsi = (int*)d_ws;
    int*  ccur   = wsi;
    unsigned* binned = (unsigned*)(wsi + 1024);
    unsigned short* t1 = (unsigned short*)(wsi + 1024);   // overlays binned
    unsigned short* srcidx = (unsigned short*)(wsi + 1024 + BCAP);
    float* dinv  = (float*)(wsi + 1024 + BCAP + BCAP / 2);
    int2* range2 = (int2*)(dinv + N);
    float* agg1  = (float*)(range2 + N);
    unsigned short* t2 = t1;                              // t1 dead before gemm2 writes
    float* outp  = (float*)d_out;

    const int G = (E + CHUNK - 1) / CHUNK;

    (void)hipMemsetAsync(ccur, 0, 1024 * sizeof(int), stream);
    k_bin<<<G, 256, 0, stream>>>(row, col, ccur, binned, E, B);
    k_fine<<<B * 8, 256, 0, stream>>>(binned, ccur, srcidx, range2, dinv, N);

    k_gemm<128, false, false><<<(N + 63) / 64, 256, 0, stream>>>(x, W1, nullptr, dinv, t1, N);
    k_gather<false><<<(N * 8 + BLK - 1) / BLK, BLK, 0, stream>>>(
        range2, srcidx, (const uint4*)t1, dinv, b1, nullptr, agg1, N);

    k_gemm<64, true, true><<<(N + 63) / 64, 256, 0, stream>>>(agg1, Wmu, Wls, dinv, t2, N);
    k_gather<true><<<(N * 8 + BLK - 1) / BLK, BLK, 0, stream>>>(
        range2, srcidx, (const uint4*)t2, dinv, bmu, bls, outp, N);
}

// Round 9
// 233.139 us; speedup vs baseline: 1.1881x; 1.1881x over previous
//
#include <hip/hip_runtime.h>
#include <hip/hip_bf16.h>

// GCN VGAE encoder. CSR via single-pass register-cached bucket binning (R7 config),
// ts table split into two 3.2MB bf16 feature planes so each gather pass is
// per-XCD-L2-resident. fp32 accumulate everywhere.
// norm factorization: agg[c] = dinv[c]*(sum_e ts[src] + ts[c]) + b, ts = (X@W)*dinv.

constexpr int BLK = 256;
constexpr int SH = 6;            // nodes per coarse bucket = 64
constexpr int CAP = 4096;        // slab capacity per bucket (mean ~2046, 45 sigma)
constexpr int CHUNK = 4096;      // edges per block in k_bin
constexpr int BMAX = 1024;       // max coarse buckets (N <= 65536)
constexpr int EPB = CHUNK / 256; // 16 register-cached edges per thread in k_bin
constexpr int EPT = 10;          // register-cached edges per thread in k_fine

typedef float vf4 __attribute__((ext_vector_type(4)));   // for nontemporal stores

__device__ __forceinline__ void fma4(float4& a, float s, const float4& w) {
    a.x = fmaf(s, w.x, a.x);
    a.y = fmaf(s, w.y, a.y);
    a.z = fmaf(s, w.z, a.z);
    a.w = fmaf(s, w.w, a.w);
}

__device__ __forceinline__ unsigned short f2bf(float f) {  // RNE
    unsigned u = __float_as_uint(f);
    return (unsigned short)((u + 0x7fffu + ((u >> 16) & 1u)) >> 16);
}

__device__ __forceinline__ void acc_bf8(float* a, uint4 v) {
    a[0] += __uint_as_float(v.x << 16);
    a[1] += __uint_as_float(v.x & 0xffff0000u);
    a[2] += __uint_as_float(v.y << 16);
    a[3] += __uint_as_float(v.y & 0xffff0000u);
    a[4] += __uint_as_float(v.z << 16);
    a[5] += __uint_as_float(v.z & 0xffff0000u);
    a[6] += __uint_as_float(v.w << 16);
    a[7] += __uint_as_float(v.w & 0xffff0000u);
}

// Single-pass binning: edges register-cached as col16<<16|row16 on the ONLY global
// read; LDS hist -> reserve slab slice -> emit from registers. Bucket = packed>>22.
__global__ __launch_bounds__(256) void k_bin(const int* __restrict__ row,
                                             const int* __restrict__ col,
                                             int* __restrict__ ccur,
                                             unsigned* __restrict__ binned,
                                             int E, int B) {
    __shared__ int h[BMAX];
    const int tid = threadIdx.x;
    for (int i = tid; i < B; i += 256) h[i] = 0;
    __syncthreads();
    const int e0 = blockIdx.x * CHUNK;
    unsigned ebuf[EPB];
    #pragma unroll
    for (int j = 0; j < EPB; ++j) {
        int e = e0 + tid + j * 256;
        ebuf[j] = (e < E) ? (((unsigned)col[e] << 16) | (unsigned)row[e]) : 0xFFFFFFFFu;
    }
    #pragma unroll
    for (int j = 0; j < EPB; ++j)
        if (ebuf[j] != 0xFFFFFFFFu) atomicAdd(&h[ebuf[j] >> 22], 1);
    __syncthreads();
    for (int i = tid; i < B; i += 256) {
        int c = h[i];
        if (c) h[i] = atomicAdd(&ccur[i], c);   // in-bucket base for this block
    }
    __syncthreads();
    #pragma unroll
    for (int j = 0; j < EPB; ++j) {
        unsigned e = ebuf[j];
        if (e != 0xFFFFFFFFu) {
            int b = e >> 22;
            int pos = atomicAdd(&h[b], 1);
            if (pos < CAP) binned[(size_t)b * CAP + pos] = e;
        }
    }
}

// One block per bucket: register-cached entries; fine histogram -> dinv + (start,end)
// ranges; dense ushort srcidx emit into the bucket's fixed-cap slab.
__global__ __launch_bounds__(256) void k_fine(const unsigned* __restrict__ binned,
                                              const int* __restrict__ ccur,
                                              unsigned short* __restrict__ srcidx,
                                              int2* __restrict__ range2,
                                              float* __restrict__ dinv, int N) {
    __shared__ int fine[64];
    const int b = blockIdx.x;
    const int n0 = b << SH;
    const int ebase = b * CAP;
    int ecnt = min(ccur[b], CAP);
    const int tid = threadIdx.x;
    if (tid < 64) fine[tid] = 0;
    __syncthreads();
    unsigned ebuf[EPT];
    #pragma unroll
    for (int j = 0; j < EPT; ++j) {
        int i = tid + j * 256;
        ebuf[j] = (i < ecnt) ? binned[ebase + i] : 0xFFFFFFFFu;
    }
    #pragma unroll
    for (int j = 0; j < EPT; ++j)
        if (ebuf[j] != 0xFFFFFFFFu) atomicAdd(&fine[(ebuf[j] >> 16) & 63], 1);
    for (int i = EPT * 256 + tid; i < ecnt; i += 256)   // overflow tail (normally empty)
        atomicAdd(&fine[(binned[ebase + i] >> 16) & 63], 1);
    __syncthreads();
    if (tid < 64) {
        int v = fine[tid], s = v;
        #pragma unroll
        for (int off = 1; off < 64; off <<= 1) {
            int u = __shfl_up(s, off, 64);
            if (tid >= off) s += u;
        }
        int base = ebase + s - v;
        int n = n0 + tid;
        if (n < N) {
            range2[n] = make_int2(base, base + v);
            dinv[n] = rsqrtf((float)v + 1.0f);
        }
        fine[tid] = base;
    }
    __syncthreads();
    #pragma unroll
    for (int j = 0; j < EPT; ++j) {
        unsigned e = ebuf[j];
        if (e != 0xFFFFFFFFu) {
            int pos = atomicAdd(&fine[(e >> 16) & 63], 1);
            srcidx[pos] = (unsigned short)(e & 0xFFFFu);
        }
    }
    for (int i = EPT * 256 + tid; i < ecnt; i += 256) {
        unsigned e = binned[ebase + i];
        int pos = atomicAdd(&fine[(e >> 16) & 63], 1);
        srcidx[pos] = (unsigned short)(e & 0xFFFFu);
    }
}

// T planes (bf16 [N][32] x2) = (op(X) @ W) * dinv[n].  4 nodes/thread.
// PIN: X given as two fp32 planes [N][32] (layer-2 input); else contiguous [N][K].
template <int K, bool RELU, bool TWO_W, bool PIN>
__global__ __launch_bounds__(256) void k_gemm(const float* __restrict__ X,
                                              const float* __restrict__ Xhi,
                                              const float* __restrict__ Wa,
                                              const float* __restrict__ Wb,
                                              const float* __restrict__ dinv,
                                              unsigned short* __restrict__ Tlo,
                                              unsigned short* __restrict__ Thi, int N) {
    __shared__ float4 Wl[K * 16];
    const int tid = threadIdx.x;
    for (int i = tid; i < K * 16; i += 256) {
        if (TWO_W) {
            int k = i >> 4, fgi = i & 15;
            const float* s = (fgi < 8) ? (Wa + k * 32 + fgi * 4)
                                       : (Wb + k * 32 + (fgi - 8) * 4);
            Wl[i] = *reinterpret_cast<const float4*>(s);
        } else {
            Wl[i] = reinterpret_cast<const float4*>(Wa)[i];
        }
    }
    __syncthreads();

    const int fg = tid & 15;
    const int ns = tid >> 4;
    const int nb = blockIdx.x * 64;
    const float4* Xv = reinterpret_cast<const float4*>(X);
    const float4* Xv2 = reinterpret_cast<const float4*>(Xhi);
    const float4 z = make_float4(0.f, 0.f, 0.f, 0.f);
    float4 acc[4] = {z, z, z, z};
    int n[4];
    bool v[4];
    #pragma unroll
    for (int i = 0; i < 4; ++i) { n[i] = nb + ns + i * 16; v[i] = n[i] < N; }

    for (int k4 = 0; k4 < K / 4; ++k4) {
        float4 xv[4];
        #pragma unroll
        for (int i = 0; i < 4; ++i) {
            if (PIN)
                xv[i] = v[i] ? ((k4 < 8) ? Xv[(size_t)n[i] * 8 + k4]
                                         : Xv2[(size_t)n[i] * 8 + (k4 - 8)]) : z;
            else
                xv[i] = v[i] ? Xv[(size_t)n[i] * (K / 4) + k4] : z;
            if (RELU) {
                xv[i].x = fmaxf(xv[i].x, 0.f); xv[i].y = fmaxf(xv[i].y, 0.f);
                xv[i].z = fmaxf(xv[i].z, 0.f); xv[i].w = fmaxf(xv[i].w, 0.f);
            }
        }
        float4 w0 = Wl[(k4 * 4 + 0) * 16 + fg];
        float4 w1 = Wl[(k4 * 4 + 1) * 16 + fg];
        float4 w2 = Wl[(k4 * 4 + 2) * 16 + fg];
        float4 w3 = Wl[(k4 * 4 + 3) * 16 + fg];
        #pragma unroll
        for (int i = 0; i < 4; ++i) {
            fma4(acc[i], xv[i].x, w0); fma4(acc[i], xv[i].y, w1);
            fma4(acc[i], xv[i].z, w2); fma4(acc[i], xv[i].w, w3);
        }
    }
    ushort4* Tp = reinterpret_cast<ushort4*>((fg < 8) ? Tlo : Thi);
    const int j = fg & 7;
    #pragma unroll
    for (int i = 0; i < 4; ++i) {
        if (v[i]) {
            float d = dinv[n[i]];
            ushort4 o;
            o.x = f2bf(acc[i].x * d); o.y = f2bf(acc[i].y * d);
            o.z = f2bf(acc[i].z * d); o.w = f2bf(acc[i].w * d);
            Tp[(size_t)n[i] * 8 + j] = o;
        }
    }
}

// One 32-feat plane pass: dst[n*32+f] = dinv[n]*(sum_{k in range(n)} Tp[srcidx[k]][f]
// + Tp[n][f]) + bias[f].  4 lanes/node, 16 B (8 bf16) each; plane (3.2MB) + srcidx
// (3.2MB) fit per-XCD L2. 8-edge unroll for MLP.
template <bool NT>
__global__ __launch_bounds__(256) void k_gather(const int2* __restrict__ range2,
                                                const unsigned short* __restrict__ srcidx,
                                                const uint4* __restrict__ Tp,
                                                const float* __restrict__ dinv,
                                                const float* __restrict__ bias,
                                                float* __restrict__ dst, int N) {
    int g = blockIdx.x * BLK + threadIdx.x;
    int n = g >> 2, q = g & 3;
    if (n >= N) return;
    int2 rg = range2[n];
    int k = rg.x, end = rg.y;
    float a[8];
    acc_bf8(a, Tp[(size_t)n * 4 + q]);   // self loop (a[] starts from this row)
    {   // acc_bf8 adds; re-init trick: subtract? simpler: init a from the self row
    }
    // (acc_bf8 on uninitialized a is UB; do explicit init instead)
    {
        uint4 s = Tp[(size_t)n * 4 + q];
        a[0] = __uint_as_float(s.x << 16);
        a[1] = __uint_as_float(s.x & 0xffff0000u);
        a[2] = __uint_as_float(s.y << 16);
        a[3] = __uint_as_float(s.y & 0xffff0000u);
        a[4] = __uint_as_float(s.z << 16);
        a[5] = __uint_as_float(s.z & 0xffff0000u);
        a[6] = __uint_as_float(s.w << 16);
        a[7] = __uint_as_float(s.w & 0xffff0000u);
    }
    for (; k < end && (k & 3); ++k)          // align to ushort4
        acc_bf8(a, Tp[(size_t)srcidx[k] * 4 + q]);
    for (; k + 8 <= end; k += 8) {
        ushort4 r0 = *reinterpret_cast<const ushort4*>(srcidx + k);
        ushort4 r1 = *reinterpret_cast<const ushort4*>(srcidx + k + 4);
        uint4 v0 = Tp[(size_t)r0.x * 4 + q];
        uint4 v1 = Tp[(size_t)r0.y * 4 + q];
        uint4 v2 = Tp[(size_t)r0.z * 4 + q];
        uint4 v3 = Tp[(size_t)r0.w * 4 + q];
        uint4 v4 = Tp[(size_t)r1.x * 4 + q];
        uint4 v5 = Tp[(size_t)r1.y * 4 + q];
        uint4 v6 = Tp[(size_t)r1.z * 4 + q];
        uint4 v7 = Tp[(size_t)r1.w * 4 + q];
        acc_bf8(a, v0); acc_bf8(a, v1); acc_bf8(a, v2); acc_bf8(a, v3);
        acc_bf8(a, v4); acc_bf8(a, v5); acc_bf8(a, v6); acc_bf8(a, v7);
    }
    if (k + 4 <= end) {
        ushort4 r0 = *reinterpret_cast<const ushort4*>(srcidx + k);
        uint4 v0 = Tp[(size_t)r0.x * 4 + q];
        uint4 v1 = Tp[(size_t)r0.y * 4 + q];
        uint4 v2 = Tp[(size_t)r0.z * 4 + q];
        uint4 v3 = Tp[(size_t)r0.w * 4 + q];
        acc_bf8(a, v0); acc_bf8(a, v1); acc_bf8(a, v2); acc_bf8(a, v3);
        k += 4;
    }
    for (; k < end; ++k)
        acc_bf8(a, Tp[(size_t)srcidx[k] * 4 + q]);

    float d = dinv[n];
    float4 b0 = reinterpret_cast<const float4*>(bias + q * 8)[0];
    float4 b1 = reinterpret_cast<const float4*>(bias + q * 8)[1];
    vf4 o0, o1;
    o0.x = fmaf(a[0], d, b0.x); o0.y = fmaf(a[1], d, b0.y);
    o0.z = fmaf(a[2], d, b0.z); o0.w = fmaf(a[3], d, b0.w);
    o1.x = fmaf(a[4], d, b1.x); o1.y = fmaf(a[5], d, b1.y);
    o1.z = fmaf(a[6], d, b1.z); o1.w = fmaf(a[7], d, b1.w);
    vf4* dp = reinterpret_cast<vf4*>(dst + (size_t)n * 32 + q * 8);
    if (NT) {   // final output: write-once, bypass-cache hint
        __builtin_nontemporal_store(o0, dp);
        __builtin_nontemporal_store(o1, dp + 1);
    } else {
        dp[0] = o0;
        dp[1] = o1;
    }
}

extern "C" void kernel_launch(void* const* d_in, const int* in_sizes, int n_in,
                              void* d_out, int out_size, void* d_ws, size_t ws_size,
                              hipStream_t stream) {
    const float* x   = (const float*)d_in[0];
    const int*   ei  = (const int*)d_in[1];
    const float* W1  = (const float*)d_in[2];
    const float* b1  = (const float*)d_in[3];
    const float* Wmu = (const float*)d_in[4];
    const float* bmu = (const float*)d_in[5];
    const float* Wls = (const float*)d_in[6];
    const float* bls = (const float*)d_in[7];

    const int N = in_sizes[0] / 128;
    const int E = in_sizes[1] / 2;
    const int* row = ei;            // sources
    const int* col = ei + E;        // targets
    const int B = (N + 63) >> SH;   // coarse buckets (<= BMAX)
    const size_t BCAP = (size_t)B * CAP;

    // ws layout (4B units):
    // [0,1024) ccur | [1024, 1024+ov) binned (overlaid after k_fine by the two bf16
    // ts planes, each N*16 ints) | srcidx ushort[BCAP] (BCAP/2 ints) | dinv[N] |
    // range2 int2[N] (2N) | agg_lo f32[32N] | agg_hi f32[32N]
    int* wsi = (int*)d_ws;
    int*  ccur   = wsi;
    unsigned* binned = (unsigned*)(wsi + 1024);
    unsigned short* t_lo = (unsigned short*)(wsi + 1024);            // plane overlays
    unsigned short* t_hi = (unsigned short*)(wsi + 1024 + 16 * (size_t)N);
    size_t ov = BCAP > (size_t)32 * N ? BCAP : (size_t)32 * N;
    unsigned short* srcidx = (unsigned short*)(wsi + 1024 + ov);
    float* dinv  = (float*)(wsi + 1024 + ov + BCAP / 2);
    int2* range2 = (int2*)(dinv + N);
    float* agg_lo = (float*)(range2 + N);
    float* agg_hi = agg_lo + 32 * (size_t)N;
    float* outp  = (float*)d_out;

    const int G = (E + CHUNK - 1) / CHUNK;
    const int GG = (N * 4 + BLK - 1) / BLK;

    (void)hipMemsetAsync(ccur, 0, 1024 * sizeof(int), stream);
    k_bin<<<G, 256, 0, stream>>>(row, col, ccur, binned, E, B);
    k_fine<<<B, 256, 0, stream>>>(binned, ccur, srcidx, range2, dinv, N);

    k_gemm<128, false, false, false><<<(N + 63) / 64, 256, 0, stream>>>(
        x, nullptr, W1, nullptr, dinv, t_lo, t_hi, N);
    k_gather<false><<<GG, BLK, 0, stream>>>(
        range2, srcidx, (const uint4*)t_lo, dinv, b1, agg_lo, N);
    k_gather<false><<<GG, BLK, 0, stream>>>(
        range2, srcidx, (const uint4*)t_hi, dinv, b1 + 32, agg_hi, N);

    k_gemm<64, true, true, true><<<(N + 63) / 64, 256, 0, stream>>>(
        agg_lo, agg_hi, Wmu, Wls, dinv, t_lo, t_hi, N);
    k_gather<true><<<GG, BLK, 0, stream>>>(
        range2, srcidx, (const uint4*)t_lo, dinv, bmu, outp, N);
    k_gather<true><<<GG, BLK, 0, stream>>>(
        range2, srcidx, (const uint4*)t_hi, dinv, bls, outp + 32 * (size_t)N, N);
}